// Round 1
// baseline (156.929 us; speedup 1.0000x reference)
//
#include <hip/hip_runtime.h>
#include <math.h>

#define MAX_SEQ   2048
#define NUM_HEADS 32
#define NUM_KV    4
#define HEAD_DIM  256
#define HIDDEN    4096
#define ROT_DIM   64
#define GROUPS    8           // NUM_HEADS / NUM_KV
#define SCALE     0.0625f     // 1/sqrt(256)
#define CHUNK     128
#define NCHUNK    (MAX_SEQ / CHUNK)   // 16

// ---------------------------------------------------------------------------
// Kernel 1: fused QKV GEMV.  rows 0..16383 -> qg, 16384..17407 -> k_raw,
// 17408..18431 -> v_raw.  One wave per row, float4 streaming.
// ---------------------------------------------------------------------------
__global__ __launch_bounds__(256) void gemv_qkv(
    const float* __restrict__ x,
    const float* __restrict__ qw,   // 16384 x 4096
    const float* __restrict__ kw,   // 1024 x 4096
    const float* __restrict__ vw,   // 1024 x 4096
    float* __restrict__ out)        // 18432
{
    const int wave = threadIdx.x >> 6;
    const int lane = threadIdx.x & 63;
    const int row  = blockIdx.x * 4 + wave;

    const float* w;
    if (row < 16384)      w = qw + (size_t)row * HIDDEN;
    else if (row < 17408) w = kw + (size_t)(row - 16384) * HIDDEN;
    else                  w = vw + (size_t)(row - 17408) * HIDDEN;

    float acc = 0.f;
#pragma unroll
    for (int it = 0; it < HIDDEN / 256; ++it) {          // 16 iters
        const int idx = it * 256 + lane * 4;
        float4 wv = *reinterpret_cast<const float4*>(w + idx);
        float4 xv = *reinterpret_cast<const float4*>(x + idx);
        acc += wv.x * xv.x + wv.y * xv.y + wv.z * xv.z + wv.w * xv.w;
    }
#pragma unroll
    for (int off = 32; off >= 1; off >>= 1) acc += __shfl_xor(acc, off);
    if (lane == 0) out[row] = acc;
}

// ---------------------------------------------------------------------------
// Kernel 2: per-head RMSNorm + partial RoPE.
// blocks 0..31: q heads (read qg[h*512 + d]); blocks 32..35: k heads.
// ---------------------------------------------------------------------------
__global__ __launch_bounds__(256) void norm_rope(
    const float* __restrict__ qkv,     // ws: qg[16384], k_raw[1024], v_raw[1024]
    const float* __restrict__ qnw,
    const float* __restrict__ knw,
    const int*   __restrict__ posp,
    float* __restrict__ qf,            // 32*256
    float* __restrict__ kf)            // 4*256
{
    const int h = blockIdx.x;
    const int d = threadIdx.x;
    const bool is_q = (h < NUM_HEADS);
    const float* src = is_q ? (qkv + h * 512)
                            : (qkv + 16384 + (h - NUM_HEADS) * HEAD_DIM);
    const float val = src[d];

    __shared__ float red[4];
    float ss = val * val;
#pragma unroll
    for (int off = 32; off >= 1; off >>= 1) ss += __shfl_xor(ss, off);
    if ((threadIdx.x & 63) == 0) red[threadIdx.x >> 6] = ss;
    __syncthreads();
    const float tot  = red[0] + red[1] + red[2] + red[3];
    const float norm = rsqrtf(tot * (1.0f / HEAD_DIM) + 1e-6f);
    const float wgt  = is_q ? qnw[d] : knw[d];
    const float nv   = val * norm * wgt;

    __shared__ float buf[HEAD_DIM];
    buf[d] = nv;
    __syncthreads();

    float outv = nv;
    if (d < ROT_DIM) {
        const int i = d & 31;
        const int pos = posp[0];
        const double inv_freq = pow(10000000.0, -(double)i / 32.0);
        const double ang = (double)pos * inv_freq;
        const float c = (float)cos(ang);
        const float s = (float)sin(ang);
        const float x1 = buf[i];
        const float x2 = buf[i + 32];
        outv = (d < 32) ? (x1 * c - x2 * s) : (x2 * c + x1 * s);
    }
    float* dst = is_q ? (qf + h * HEAD_DIM) : (kf + (h - NUM_HEADS) * HEAD_DIM);
    dst[d] = outv;
}

// ---------------------------------------------------------------------------
// Kernel 3: flash-decode partials.  grid = (32 heads, 16 chunks).
// Each block: scores for CHUNK positions (wave per position, float4 dot),
// chunk-local softmax partials (m, l, acc[256]) -> workspace.
// Position s == pos uses the freshly computed k/v (cache not mutated).
// ---------------------------------------------------------------------------
__global__ __launch_bounds__(256) void attn_partial(
    const float* __restrict__ qf,       // 32*256
    const float* __restrict__ kcache,   // 4*2048*256
    const float* __restrict__ vcache,
    const float* __restrict__ kf,       // 4*256 new k
    const float* __restrict__ vnew,     // 4*256 new v (raw proj)
    const int*   __restrict__ posp,
    float* __restrict__ part_m,         // 512
    float* __restrict__ part_l,         // 512
    float* __restrict__ part_acc)       // 512*256
{
    const int h   = blockIdx.x;
    const int c   = blockIdx.y;
    const int pos = posp[0];
    const int s0  = c * CHUNK;
    const int s1  = min(s0 + CHUNK, pos + 1);
    const int pid = h * NCHUNK + c;
    const int tid = threadIdx.x;

    if (s0 > pos) {                       // empty chunk
        if (tid == 0) { part_m[pid] = -1e30f; part_l[pid] = 0.f; }
        part_acc[(size_t)pid * HEAD_DIM + tid] = 0.f;
        return;
    }

    const int kv = h >> 3;                // GROUPS = 8
    const float* kbase = kcache + (size_t)kv * MAX_SEQ * HEAD_DIM;
    const float* vbase = vcache + (size_t)kv * MAX_SEQ * HEAD_DIM;

    const int lane = tid & 63;
    const int wave = tid >> 6;
    const float4 qv = *reinterpret_cast<const float4*>(qf + h * HEAD_DIM + lane * 4);

    __shared__ float sc[CHUNK];
    for (int s = s0 + wave; s < s0 + CHUNK; s += 4) {
        float score = -1e30f;
        if (s < s1) {
            const float* krow = (s == pos) ? (kf + kv * HEAD_DIM)
                                           : (kbase + (size_t)s * HEAD_DIM);
            float4 kr = *reinterpret_cast<const float4*>(krow + lane * 4);
            float p = qv.x * kr.x + qv.y * kr.y + qv.z * kr.z + qv.w * kr.w;
#pragma unroll
            for (int off = 32; off >= 1; off >>= 1) p += __shfl_xor(p, off);
            score = p * SCALE;
        }
        if (lane == 0) sc[s - s0] = score;
    }
    __syncthreads();

    float m = -1e30f;
    for (int i = 0; i < CHUNK; ++i) m = fmaxf(m, sc[i]);

    const int d = tid;
    float acc = 0.f;
    float l   = 0.f;
    for (int s = s0; s < s1; ++s) {
        const float p = expf(sc[s - s0] - m);
        const float* vrow = (s == pos) ? (vnew + kv * HEAD_DIM)
                                       : (vbase + (size_t)s * HEAD_DIM);
        acc += p * vrow[d];
        l   += p;
    }
    if (tid == 0) { part_m[pid] = m; part_l[pid] = l; }
    part_acc[(size_t)pid * HEAD_DIM + d] = acc;
}

// ---------------------------------------------------------------------------
// Kernel 4: combine partials across chunks + apply sigmoid gate.
// grid = 32 heads, 256 threads (one per dim).
// ---------------------------------------------------------------------------
__global__ __launch_bounds__(256) void attn_combine(
    const float* __restrict__ part_m,
    const float* __restrict__ part_l,
    const float* __restrict__ part_acc,
    const float* __restrict__ qkv,      // gate at h*512 + 256 + d
    float* __restrict__ attn_gated)     // 8192
{
    const int h = blockIdx.x;
    const int d = threadIdx.x;

    float M = -1e30f;
#pragma unroll
    for (int c = 0; c < NCHUNK; ++c) M = fmaxf(M, part_m[h * NCHUNK + c]);

    float L = 0.f, acc = 0.f;
#pragma unroll
    for (int c = 0; c < NCHUNK; ++c) {
        const float lc = part_l[h * NCHUNK + c];
        if (lc > 0.f) {
            const float w = expf(part_m[h * NCHUNK + c] - M);
            L   += lc * w;
            acc += part_acc[(size_t)(h * NCHUNK + c) * HEAD_DIM + d] * w;
        }
    }
    const float o   = acc / L;
    const float g   = qkv[h * 512 + 256 + d];
    const float sig = 1.0f / (1.0f + expf(-g));
    attn_gated[h * HEAD_DIM + d] = o * sig;
}

// ---------------------------------------------------------------------------
// Kernel 5: O-projection GEMV.  4096 rows x 8192.  One wave per row.
// ---------------------------------------------------------------------------
__global__ __launch_bounds__(256) void gemv_o(
    const float* __restrict__ vec,      // 8192 gated attention output
    const float* __restrict__ w,        // 4096 x 8192
    float* __restrict__ out)            // 4096
{
    const int wave = threadIdx.x >> 6;
    const int lane = threadIdx.x & 63;
    const int row  = blockIdx.x * 4 + wave;
    const float* wr = w + (size_t)row * 8192;

    float acc = 0.f;
#pragma unroll
    for (int it = 0; it < 8192 / 256; ++it) {            // 32 iters
        const int idx = it * 256 + lane * 4;
        float4 wv = *reinterpret_cast<const float4*>(wr + idx);
        float4 xv = *reinterpret_cast<const float4*>(vec + idx);
        acc += wv.x * xv.x + wv.y * xv.y + wv.z * xv.z + wv.w * xv.w;
    }
#pragma unroll
    for (int off = 32; off >= 1; off >>= 1) acc += __shfl_xor(acc, off);
    if (lane == 0) out[row] = acc;
}

// ---------------------------------------------------------------------------
extern "C" void kernel_launch(void* const* d_in, const int* in_sizes, int n_in,
                              void* d_out, int out_size, void* d_ws, size_t ws_size,
                              hipStream_t stream) {
    const float* x        = (const float*)d_in[0];
    const int*   position = (const int*)  d_in[1];
    // d_in[2] mask, d_in[5] onehot: derived from position on-device instead.
    const float* k_cache  = (const float*)d_in[3];
    const float* v_cache  = (const float*)d_in[4];
    const float* q_proj_w = (const float*)d_in[6];
    const float* k_proj_w = (const float*)d_in[7];
    const float* v_proj_w = (const float*)d_in[8];
    const float* o_proj_w = (const float*)d_in[9];
    const float* q_norm_w = (const float*)d_in[10];
    const float* k_norm_w = (const float*)d_in[11];
    float* out = (float*)d_out;

    float* ws         = (float*)d_ws;
    float* qkv        = ws;                 // 18432  (qg | k_raw | v_raw)
    float* qf         = ws + 18432;         // 8192
    float* kf         = ws + 26624;         // 1024
    float* part_m     = ws + 27648;         // 512
    float* part_l     = ws + 28160;         // 512
    float* part_acc   = ws + 28672;         // 131072
    float* attn_gated = ws + 159744;        // 8192

    gemv_qkv<<<18432 / 4, 256, 0, stream>>>(x, q_proj_w, k_proj_w, v_proj_w, qkv);
    norm_rope<<<NUM_HEADS + NUM_KV, 256, 0, stream>>>(qkv, q_norm_w, k_norm_w,
                                                      position, qf, kf);
    dim3 g3(NUM_HEADS, NCHUNK);
    attn_partial<<<g3, 256, 0, stream>>>(qf, k_cache, v_cache, kf, qkv + 17408,
                                         position, part_m, part_l, part_acc);
    attn_combine<<<NUM_HEADS, 256, 0, stream>>>(part_m, part_l, part_acc, qkv,
                                                attn_gated);
    gemv_o<<<4096 / 4, 256, 0, stream>>>(attn_gated, o_proj_w, out);
}

// Round 2
// 108.791 us; speedup vs baseline: 1.4425x; 1.4425x over previous
//
#include <hip/hip_runtime.h>
#include <math.h>

#define MAX_SEQ   2048
#define NUM_HEADS 32
#define NUM_KV    4
#define HEAD_DIM  256
#define HIDDEN    4096
#define ROT_DIM   64
#define GROUPS    8           // NUM_HEADS / NUM_KV
#define SCALE     0.0625f     // 1/sqrt(256)
#define CHUNK     32          // must be 32 (matches reduce-group width)
#define NCHUNK    (MAX_SEQ / CHUNK)   // 64

typedef float f4 __attribute__((ext_vector_type(4)));

__device__ inline f4 ntload4(const float* p) {
    return __builtin_nontemporal_load(reinterpret_cast<const f4*>(p));
}

// ---------------------------------------------------------------------------
// Kernel 1: fused QKV GEMV.  rows 0..16383 -> qg, 16384..17407 -> k_raw,
// 17408..18431 -> v_raw.  One wave per row, float4 streaming, NT weight loads.
// ---------------------------------------------------------------------------
__global__ __launch_bounds__(256) void gemv_qkv(
    const float* __restrict__ x,
    const float* __restrict__ qw,   // 16384 x 4096
    const float* __restrict__ kw,   // 1024 x 4096
    const float* __restrict__ vw,   // 1024 x 4096
    float* __restrict__ out)        // 18432
{
    const int wave = threadIdx.x >> 6;
    const int lane = threadIdx.x & 63;
    const int row  = blockIdx.x * 4 + wave;

    const float* w;
    if (row < 16384)      w = qw + (size_t)row * HIDDEN;
    else if (row < 17408) w = kw + (size_t)(row - 16384) * HIDDEN;
    else                  w = vw + (size_t)(row - 17408) * HIDDEN;

    float acc = 0.f;
#pragma unroll
    for (int it = 0; it < HIDDEN / 256; ++it) {          // 16 iters
        const int idx = it * 256 + lane * 4;
        f4 wv = ntload4(w + idx);
        f4 xv = *reinterpret_cast<const f4*>(x + idx);
        acc += wv[0] * xv[0] + wv[1] * xv[1] + wv[2] * xv[2] + wv[3] * xv[3];
    }
#pragma unroll
    for (int off = 32; off >= 1; off >>= 1) acc += __shfl_xor(acc, off);
    if (lane == 0) out[row] = acc;
}

// ---------------------------------------------------------------------------
// Kernel 2: per-head RMSNorm + partial RoPE.
// blocks 0..31: q heads (read qg[h*512 + d]); blocks 32..35: k heads.
// ---------------------------------------------------------------------------
__global__ __launch_bounds__(256) void norm_rope(
    const float* __restrict__ qkv,     // ws: qg[16384], k_raw[1024], v_raw[1024]
    const float* __restrict__ qnw,
    const float* __restrict__ knw,
    const int*   __restrict__ posp,
    float* __restrict__ qf,            // 32*256
    float* __restrict__ kf)            // 4*256
{
    const int h = blockIdx.x;
    const int d = threadIdx.x;
    const bool is_q = (h < NUM_HEADS);
    const float* src = is_q ? (qkv + h * 512)
                            : (qkv + 16384 + (h - NUM_HEADS) * HEAD_DIM);
    const float val = src[d];

    __shared__ float red[4];
    float ss = val * val;
#pragma unroll
    for (int off = 32; off >= 1; off >>= 1) ss += __shfl_xor(ss, off);
    if ((threadIdx.x & 63) == 0) red[threadIdx.x >> 6] = ss;
    __syncthreads();
    const float tot  = red[0] + red[1] + red[2] + red[3];
    const float norm = rsqrtf(tot * (1.0f / HEAD_DIM) + 1e-6f);
    const float wgt  = is_q ? qnw[d] : knw[d];
    const float nv   = val * norm * wgt;

    __shared__ float buf[HEAD_DIM];
    buf[d] = nv;
    __syncthreads();

    float outv = nv;
    if (d < ROT_DIM) {
        const int i = d & 31;
        const int pos = posp[0];
        const double inv_freq = pow(10000000.0, -(double)i / 32.0);
        const double ang = (double)pos * inv_freq;
        const float c = (float)cos(ang);
        const float s = (float)sin(ang);
        const float x1 = buf[i];
        const float x2 = buf[i + 32];
        outv = (d < 32) ? (x1 * c - x2 * s) : (x2 * c + x1 * s);
    }
    float* dst = is_q ? (qf + h * HEAD_DIM) : (kf + (h - NUM_HEADS) * HEAD_DIM);
    dst[d] = outv;
}

// ---------------------------------------------------------------------------
// Kernel 3: flash-decode partials, GQA-grouped.
// grid = (NUM_KV, NCHUNK).  Each block: CHUNK=32 positions for ALL 8 q-heads
// of one kv group.  K row loaded once -> 8 simultaneous dots; V row loaded
// once -> 8 accumulators.  Position s == pos substitutes fresh k/v (cache
// is NOT mutated).
// ---------------------------------------------------------------------------
__global__ __launch_bounds__(256) void attn_partial(
    const float* __restrict__ qf,       // 32*256
    const float* __restrict__ kcache,   // 4*2048*256
    const float* __restrict__ vcache,
    const float* __restrict__ kf,       // 4*256 new k
    const float* __restrict__ vnew,     // 4*256 new v (raw proj)
    const int*   __restrict__ posp,
    float* __restrict__ part_m,         // 32*NCHUNK
    float* __restrict__ part_l,         // 32*NCHUNK
    float* __restrict__ part_acc)       // 32*NCHUNK*256
{
    const int kv  = blockIdx.x;
    const int c   = blockIdx.y;
    const int pos = posp[0];
    const int s0  = c * CHUNK;
    const int s1  = min(s0 + CHUNK, pos + 1);
    const int tid = threadIdx.x;

    if (s0 > pos) {                       // empty chunk: mark all 8 heads
        if (tid == 0) {
#pragma unroll
            for (int g = 0; g < GROUPS; ++g) {
                const int pid = (kv * GROUPS + g) * NCHUNK + c;
                part_m[pid] = -1e30f; part_l[pid] = 0.f;
            }
        }
        return;
    }

    const float* kbase = kcache + (size_t)kv * MAX_SEQ * HEAD_DIM;
    const float* vbase = vcache + (size_t)kv * MAX_SEQ * HEAD_DIM;

    const int lane = tid & 63;
    const int wave = tid >> 6;

    // q fragments for all 8 heads of this group
    f4 q8[GROUPS];
#pragma unroll
    for (int g = 0; g < GROUPS; ++g)
        q8[g] = *reinterpret_cast<const f4*>(qf + (kv * GROUPS + g) * HEAD_DIM + lane * 4);

    __shared__ float sc[GROUPS][CHUNK];   // raw scores
    __shared__ float pl[GROUPS][CHUNK];   // exp(score - m)
    __shared__ float mh[GROUPS], lh[GROUPS];

    // ---- score phase: wave per position, 8 iters ----
    for (int i = wave; i < CHUNK; i += 4) {
        const int s = s0 + i;
        float part[GROUPS];
#pragma unroll
        for (int g = 0; g < GROUPS; ++g) part[g] = 0.f;
        const bool valid = (s < s1);
        if (valid) {
            const float* krow = (s == pos) ? (kf + kv * HEAD_DIM)
                                           : (kbase + (size_t)s * HEAD_DIM);
            f4 kvec = *reinterpret_cast<const f4*>(krow + lane * 4);
#pragma unroll
            for (int g = 0; g < GROUPS; ++g) {
                f4 t = q8[g] * kvec;
                part[g] += t[0] + t[1] + t[2] + t[3];
            }
        }
#pragma unroll
        for (int off = 32; off >= 1; off >>= 1) {
#pragma unroll
            for (int g = 0; g < GROUPS; ++g)
                part[g] += __shfl_xor(part[g], off);
        }
        if (lane == 0) {
#pragma unroll
            for (int g = 0; g < GROUPS; ++g)
                sc[g][i] = valid ? part[g] * SCALE : -1e30f;
        }
    }
    __syncthreads();

    // ---- softmax partials: thread t -> (head t>>5, pos t&31) ----
    {
        const int h = tid >> 5;           // 0..7
        const int j = tid & 31;           // 0..31 == CHUNK
        float v = sc[h][j];
        float m = v;
#pragma unroll
        for (int off = 16; off >= 1; off >>= 1)
            m = fmaxf(m, __shfl_xor(m, off));   // stays within 32-group
        const float p = expf(v - m);            // -1e30 - m -> exp(-inf) = 0
        pl[h][j] = p;
        float ls = p;
#pragma unroll
        for (int off = 16; off >= 1; off >>= 1)
            ls += __shfl_xor(ls, off);
        if (j == 0) { mh[h] = m; lh[h] = ls; }
    }
    __syncthreads();

    // ---- PV phase: thread d accumulates 8 heads against one V stream ----
    const int d = tid;
    float acc[GROUPS];
#pragma unroll
    for (int g = 0; g < GROUPS; ++g) acc[g] = 0.f;
    for (int s = s0; s < s1; ++s) {
        const float* vrow = (s == pos) ? (vnew + kv * HEAD_DIM)
                                       : (vbase + (size_t)s * HEAD_DIM);
        const float v = vrow[d];
        const int i = s - s0;
#pragma unroll
        for (int g = 0; g < GROUPS; ++g) acc[g] += pl[g][i] * v;
    }
#pragma unroll
    for (int g = 0; g < GROUPS; ++g) {
        const int pid = (kv * GROUPS + g) * NCHUNK + c;
        part_acc[(size_t)pid * HEAD_DIM + d] = acc[g];
        if (tid == 0) { part_m[pid] = mh[g]; part_l[pid] = lh[g]; }
    }
}

// ---------------------------------------------------------------------------
// Kernel 4: combine partials across chunks + apply sigmoid gate.
// grid = 32 heads, 256 threads (one per dim).
// ---------------------------------------------------------------------------
__global__ __launch_bounds__(256) void attn_combine(
    const float* __restrict__ part_m,
    const float* __restrict__ part_l,
    const float* __restrict__ part_acc,
    const float* __restrict__ qkv,      // gate at h*512 + 256 + d
    float* __restrict__ attn_gated)     // 8192
{
    const int h = blockIdx.x;
    const int d = threadIdx.x;

    float M = -1e30f;
    for (int c = 0; c < NCHUNK; ++c) M = fmaxf(M, part_m[h * NCHUNK + c]);

    float L = 0.f, acc = 0.f;
    for (int c = 0; c < NCHUNK; ++c) {
        const float lc = part_l[h * NCHUNK + c];
        if (lc > 0.f) {
            const float w = expf(part_m[h * NCHUNK + c] - M);
            L   += lc * w;
            acc += part_acc[(size_t)(h * NCHUNK + c) * HEAD_DIM + d] * w;
        }
    }
    const float o   = acc / L;
    const float g   = qkv[h * 512 + 256 + d];
    const float sig = 1.0f / (1.0f + expf(-g));
    attn_gated[h * HEAD_DIM + d] = o * sig;
}

// ---------------------------------------------------------------------------
// Kernel 5: O-projection GEMV.  4096 rows x 8192.  One wave per row.
// ---------------------------------------------------------------------------
__global__ __launch_bounds__(256) void gemv_o(
    const float* __restrict__ vec,      // 8192 gated attention output
    const float* __restrict__ w,        // 4096 x 8192
    float* __restrict__ out)            // 4096
{
    const int wave = threadIdx.x >> 6;
    const int lane = threadIdx.x & 63;
    const int row  = blockIdx.x * 4 + wave;
    const float* wr = w + (size_t)row * 8192;

    float acc = 0.f;
#pragma unroll
    for (int it = 0; it < 8192 / 256; ++it) {            // 32 iters
        const int idx = it * 256 + lane * 4;
        f4 wv = ntload4(wr + idx);
        f4 xv = *reinterpret_cast<const f4*>(vec + idx);
        acc += wv[0] * xv[0] + wv[1] * xv[1] + wv[2] * xv[2] + wv[3] * xv[3];
    }
#pragma unroll
    for (int off = 32; off >= 1; off >>= 1) acc += __shfl_xor(acc, off);
    if (lane == 0) out[row] = acc;
}

// ---------------------------------------------------------------------------
extern "C" void kernel_launch(void* const* d_in, const int* in_sizes, int n_in,
                              void* d_out, int out_size, void* d_ws, size_t ws_size,
                              hipStream_t stream) {
    const float* x        = (const float*)d_in[0];
    const int*   position = (const int*)  d_in[1];
    // d_in[2] mask, d_in[5] onehot: derived from position on-device instead.
    const float* k_cache  = (const float*)d_in[3];
    const float* v_cache  = (const float*)d_in[4];
    const float* q_proj_w = (const float*)d_in[6];
    const float* k_proj_w = (const float*)d_in[7];
    const float* v_proj_w = (const float*)d_in[8];
    const float* o_proj_w = (const float*)d_in[9];
    const float* q_norm_w = (const float*)d_in[10];
    const float* k_norm_w = (const float*)d_in[11];
    float* out = (float*)d_out;

    float* ws         = (float*)d_ws;
    float* qkv        = ws;                  // 18432  (qg | k_raw | v_raw)
    float* qf         = ws + 18432;          // 8192
    float* kf         = ws + 26624;          // 1024
    float* part_m     = ws + 27648;          // 2048
    float* part_l     = ws + 29696;          // 2048
    float* part_acc   = ws + 31744;          // 524288
    float* attn_gated = ws + 556032;         // 8192

    gemv_qkv<<<18432 / 4, 256, 0, stream>>>(x, q_proj_w, k_proj_w, v_proj_w, qkv);
    norm_rope<<<NUM_HEADS + NUM_KV, 256, 0, stream>>>(qkv, q_norm_w, k_norm_w,
                                                      position, qf, kf);
    dim3 g3(NUM_KV, NCHUNK);
    attn_partial<<<g3, 256, 0, stream>>>(qf, k_cache, v_cache, kf, qkv + 17408,
                                         position, part_m, part_l, part_acc);
    attn_combine<<<NUM_HEADS, 256, 0, stream>>>(part_m, part_l, part_acc, qkv,
                                                attn_gated);
    gemv_o<<<4096 / 4, 256, 0, stream>>>(attn_gated, o_proj_w, out);
}